// Round 9
// baseline (9454.382 us; speedup 1.0000x reference)
//
#include <hip/hip_runtime.h>
#include <hip/hip_cooperative_groups.h>
#include <math.h>

namespace cg = cooperative_groups;

typedef unsigned short u16;
typedef __bf16 bf16x8 __attribute__((ext_vector_type(8)));
typedef float f32x4 __attribute__((ext_vector_type(4)));
typedef unsigned short u16x8 __attribute__((ext_vector_type(8)));
typedef unsigned short u16x4 __attribute__((ext_vector_type(4)));
typedef int i32x4 __attribute__((ext_vector_type(4)));

#define NBLK 256
#define NTHR 1024        // 16 waves = 8 row-groups x 2 col-halves -> 4 waves/SIMD
#define BB 1024
#define TT 256
#define EE 512
#define UU 1024
#define K0 1536          // A0 row: [emb(512) | h0(1024)]
#define K1 2048          // A1 row: [h0'(1024) | h1(1024)]
#define NK0 48           // K0/32
#define NK1 64           // K1/32
#define KTL0 32          // L0: bB kt-prefix resident in LDS (of 48)
#define KTL1 16          // L1: bB kt-prefix resident in LDS (of 64)
#define HN0 ((size_t)BB * K0)
#define HN1 ((size_t)BB * K1)
// LDS: bA 2 frag-cols (L0 96KB / L1 128KB) + bB prefix (L0 64KB / L1 32KB) = 160KB
#define LDS_BYTES 163840

// bar layout (ints)
#define ROSTER_BASE 0            // [0..7] per-XCD block count
#define FLAG_BASE 32             // 8 * 256 arrival flags
#define EPOCH_BASE (32 + 2048)   // 8 epochs, 32-int stride
#define BAR_INTS 2560

#define AUX_SC0 1        // bypass L1, served by local L2 (A stream: no L1 reuse)
#define AUX_L1  0        // weights: keep L1 (waves share the same lines)

__device__ i32x4 llvm_amdgcn_raw_buffer_load_i32x4(i32x4 srsrc, int voffset, int soffset,
                                                   int aux) __asm("llvm.amdgcn.raw.buffer.load.v4i32");

__device__ __forceinline__ i32x4 make_srd(const void* p) {
  union { const void* p; int i[2]; } u; u.p = p;
  i32x4 r; r.x = u.i[0]; r.y = u.i[1]; r.z = -1; r.w = 0x00020000;
  return r;
}

__device__ __forceinline__ u16 f2bf(float f) {
  unsigned u = __builtin_bit_cast(unsigned, f);
  u += 0x7fffu + ((u >> 16) & 1u);
  return (u16)(u >> 16);
}
__device__ __forceinline__ float bf2f(u16 h) {
  return __builtin_bit_cast(float, ((unsigned)h) << 16);
}
__device__ __forceinline__ float fast_tanh(float x) {
  x = fminf(fmaxf(x, -15.f), 15.f);
  float e = __expf(2.f * x);
  return (e - 1.f) / (e + 1.f);
}

// weight transpose + MFMA-fragment swizzle (r2/r3-verified layout):
// elem g = (cb*NK + kt)*64 + lane (8 u16 each); value = Wfull[k][n],
// n = cb*16 + (lane&15), k = kt*32 + (lane>>4)*8 + e
template<int K, int KLOW>
__device__ __forceinline__ void wfill(u16* __restrict__ Wt,
    const float* __restrict__ Wl, const float* __restrict__ Wh, int gstart) {
  constexpr int NK = K / 32;
  constexpr int NG = 1024 * K / 8;
  for (int g = gstart; g < NG; g += NBLK * NTHR) {
    const int lane = g & 63;
    const int r = g >> 6;
    const int kt = r % NK;
    const int cb = r / NK;
    const int n = cb * 16 + (lane & 15);
    const int kb = kt * 32 + (lane >> 4) * 8;
    u16x8 o;
#pragma unroll
    for (int e = 0; e < 8; ++e) {
      const int k = kb + e;
      const float v = (k < KLOW) ? Wl[(size_t)k * UU + n] : Wh[(size_t)(k - KLOW) * UU + n];
      o[e] = f2bf(v);
    }
    *(u16x8*)(Wt + (size_t)g * 8) = o;
  }
}

// XCD-local barrier: agent-scope flags + leader + epoch; guarded polls bail instead of hanging.
__device__ __forceinline__ void xbar(int* __restrict__ bar, int xcc, int slot, int nx,
                                     int tgt, int tid) {
  __syncthreads();   // all waves' stores drained before arrival
  if (tid < 64) {
    if (tid == 0)
      __hip_atomic_store(&bar[FLAG_BASE + xcc * 256 + slot], tgt,
                         __ATOMIC_RELAXED, __HIP_MEMORY_SCOPE_AGENT);
    if (slot == 0) {
      for (int base = 0; base < nx; base += 64) {
        const int i = base + tid;
        const bool act = (i < nx);
        int guard = 0;
        bool done = false;
        do {
          int v = act ? __hip_atomic_load(&bar[FLAG_BASE + xcc * 256 + i],
                                          __ATOMIC_RELAXED, __HIP_MEMORY_SCOPE_AGENT)
                      : tgt;
          done = __all(v >= tgt) != 0;
        } while (!done && ++guard < 300000);
      }
      if (tid == 0)
        __hip_atomic_store(&bar[EPOCH_BASE + xcc * 32], tgt,
                           __ATOMIC_RELAXED, __HIP_MEMORY_SCOPE_AGENT);
    } else if (tid == 0) {
      int guard = 0;
      while (__hip_atomic_load(&bar[EPOCH_BASE + xcc * 32],
                               __ATOMIC_RELAXED, __HIP_MEMORY_SCOPE_AGENT) < tgt
             && ++guard < 600000)
        __builtin_amdgcn_s_sleep(8);
    }
  }
  __syncthreads();
}

// 2 MFMA for one kt: b0/b1 from pointers (LDS or global)
__device__ __forceinline__ void mf2(const i32x4& av,
    const u16* __restrict__ p0, const u16* __restrict__ p1,
    size_t koff, int lo, f32x4 (&acc)[2]) {
  u16x8 b0 = *(const u16x8*)(p0 + koff + lo);
  u16x8 b1 = *(const u16x8*)(p1 + koff + lo);
  bf16x8 fa0 = __builtin_bit_cast(bf16x8, av);
  bf16x8 fb0 = __builtin_bit_cast(bf16x8, b0);
  bf16x8 fb1 = __builtin_bit_cast(bf16x8, b1);
  acc[0] = __builtin_amdgcn_mfma_f32_16x16x32_bf16(fa0, fb0, acc[0], 0, 0, 0);
  acc[1] = __builtin_amdgcn_mfma_f32_16x16x32_bf16(fa0, fb1, acc[1], 0, 0, 0);
}

// 2 MFMA for one kt: b0/b1 from pre-loaded registers (suffix path)
__device__ __forceinline__ void mf2r(const i32x4& av,
    const i32x4& b0v, const i32x4& b1v, f32x4 (&acc)[2]) {
  bf16x8 fa0 = __builtin_bit_cast(bf16x8, av);
  bf16x8 fb0 = __builtin_bit_cast(bf16x8, b0v);
  bf16x8 fb1 = __builtin_bit_cast(bf16x8, b1v);
  acc[0] = __builtin_amdgcn_mfma_f32_16x16x32_bf16(fa0, fb0, acc[0], 0, 0, 0);
  acc[1] = __builtin_amdgcn_mfma_f32_16x16x32_bf16(fa0, fb1, acc[1], 0, 0, 0);
}

// ch=0 wave: C[16x32] += A[16xK] @ B-LDS (frag-cols 0,1 of the stripe, full K).
// A batched in 8-kt double-buffered groups; sched_barrier pins issue order (r8-proven).
template<int K>
__device__ __forceinline__ void gemmA(const i32x4& srdA, int voA,
    const u16* __restrict__ bA, int lane, f32x4 (&acc)[2]) {
  constexpr int NK = K / 32;
  constexpr int NG = NK / 8;
  const int lo = lane * 8;
  const u16* p0 = bA;
  const u16* p1 = bA + (size_t)NK * 512;
  i32x4 aE[8], aO[8];
#pragma unroll
  for (int j = 0; j < 8; ++j)
    aE[j] = llvm_amdgcn_raw_buffer_load_i32x4(srdA, voA + j * 64, 0, AUX_SC0);
#pragma unroll
  for (int g = 0; g < NG; ++g) {
    if (g + 1 < NG) {
#pragma unroll
      for (int j = 0; j < 8; ++j) {
        i32x4 v = llvm_amdgcn_raw_buffer_load_i32x4(srdA, voA + ((g + 1) * 8 + j) * 64, 0, AUX_SC0);
        if ((g & 1) == 0) aO[j] = v; else aE[j] = v;
      }
    }
    __builtin_amdgcn_sched_barrier(0);
#pragma unroll
    for (int j = 0; j < 8; ++j) {
      const int kt = g * 8 + j;
      if ((g & 1) == 0) mf2(aE[j], p0, p1, (size_t)kt * 512, lo, acc);
      else              mf2(aO[j], p0, p1, (size_t)kt * 512, lo, acc);
    }
    __builtin_amdgcn_sched_barrier(0);
  }
}

// ch=1 wave: C[16x32] += A[16xK] @ B (frag-cols 2,3): prefix kt<KTL from LDS,
// suffix from global in 4-kt double-buffered {4A+8B} groups (r8-proven skeleton).
template<int K, int KTL>
__device__ __forceinline__ void gemmB(const i32x4& srdA, int voA,
    const u16* __restrict__ bP, const u16* __restrict__ gB2, int lane,
    f32x4 (&acc)[2]) {
  constexpr int NK = K / 32;
  constexpr int NGP = KTL / 8;          // L0: 4, L1: 2
  constexpr int NGS = (NK - KTL) / 4;   // L0: 4, L1: 12
  const int lo = lane * 8;
  const int lob = lane * 16;
  const u16* p0 = bP;
  const u16* p1 = bP + (size_t)KTL * 512;
  i32x4 srdB = make_srd(gB2);
  i32x4 aE[8], aO[8];
  i32x4 sAE[4], sBE[8], sAO[4], sBO[8];
#pragma unroll
  for (int j = 0; j < 8; ++j)
    aE[j] = llvm_amdgcn_raw_buffer_load_i32x4(srdA, voA + j * 64, 0, AUX_SC0);
#pragma unroll
  for (int g = 0; g < NGP; ++g) {
    if (g + 1 < NGP) {
#pragma unroll
      for (int j = 0; j < 8; ++j) {
        i32x4 v = llvm_amdgcn_raw_buffer_load_i32x4(srdA, voA + ((g + 1) * 8 + j) * 64, 0, AUX_SC0);
        if ((g & 1) == 0) aO[j] = v; else aE[j] = v;
      }
    } else {
      // last prefix group: prefetch suffix group 0 (4 A + 8 B)
#pragma unroll
      for (int j = 0; j < 4; ++j) {
        sAE[j] = llvm_amdgcn_raw_buffer_load_i32x4(srdA, voA + (KTL + j) * 64, 0, AUX_SC0);
        sBE[2 * j]     = llvm_amdgcn_raw_buffer_load_i32x4(srdB, (0 * NK + KTL + j) * 1024 + lob, 0, AUX_L1);
        sBE[2 * j + 1] = llvm_amdgcn_raw_buffer_load_i32x4(srdB, (1 * NK + KTL + j) * 1024 + lob, 0, AUX_L1);
      }
    }
    __builtin_amdgcn_sched_barrier(0);
#pragma unroll
    for (int j = 0; j < 8; ++j) {
      const int kt = g * 8 + j;
      if ((g & 1) == 0) mf2(aE[j], p0, p1, (size_t)kt * 512, lo, acc);
      else              mf2(aO[j], p0, p1, (size_t)kt * 512, lo, acc);
    }
    __builtin_amdgcn_sched_barrier(0);
  }
#pragma unroll
  for (int s = 0; s < NGS; ++s) {
    if (s + 1 < NGS) {
      const int kb = KTL + (s + 1) * 4;
#pragma unroll
      for (int j = 0; j < 4; ++j) {
        i32x4 va = llvm_amdgcn_raw_buffer_load_i32x4(srdA, voA + (kb + j) * 64, 0, AUX_SC0);
        i32x4 v0 = llvm_amdgcn_raw_buffer_load_i32x4(srdB, (0 * NK + kb + j) * 1024 + lob, 0, AUX_L1);
        i32x4 v1 = llvm_amdgcn_raw_buffer_load_i32x4(srdB, (1 * NK + kb + j) * 1024 + lob, 0, AUX_L1);
        if ((s & 1) == 0) { sAO[j] = va; sBO[2 * j] = v0; sBO[2 * j + 1] = v1; }
        else              { sAE[j] = va; sBE[2 * j] = v0; sBE[2 * j + 1] = v1; }
      }
    }
    __builtin_amdgcn_sched_barrier(0);
#pragma unroll
    for (int j = 0; j < 4; ++j) {
      if ((s & 1) == 0) mf2r(sAE[j], sBE[2 * j], sBE[2 * j + 1], acc);
      else              mf2r(sAO[j], sBO[2 * j], sBO[2 * j + 1], acc);
    }
    __builtin_amdgcn_sched_barrier(0);
  }
}

// fallback (job != slot, only when nx < 32): all-global pointer loads
template<int K>
__device__ __forceinline__ void gemmF(const i32x4& srdA, int voA,
    const u16* __restrict__ q0, const u16* __restrict__ q1, int lane,
    f32x4 (&acc)[2]) {
  constexpr int NK = K / 32;
  const int lo = lane * 8;
#pragma unroll 8
  for (int kt = 0; kt < NK; ++kt) {
    i32x4 a0 = llvm_amdgcn_raw_buffer_load_i32x4(srdA, voA + kt * 64, 0, AUX_SC0);
    mf2(a0, q0, q1, (size_t)kt * 512, lo, acc);
  }
}

// layer-0 job jl (0..15): stage emb(tk+1) for rows jl*8..+8, then h0'(tk) GEMM
__device__ __forceinline__ void do_l0(int tk, int xcc, int jl, bool uselds,
    const u16* __restrict__ ldsb, const u16* __restrict__ Wt0,
    const int* __restrict__ inputs, const float* __restrict__ emb,
    const float* __restrict__ b0, u16* __restrict__ A0, u16* __restrict__ A1,
    int tid)
{
  const int lane = tid & 63, wv = tid >> 6, q = lane >> 4, l16 = lane & 15;
  const int ch = (wv >> 2) & 1;                 // col-half: frag-cols {0,1} or {2,3}
  const int rg = (wv & 3) + ((wv >> 3) << 2);   // row-group 0..7 (SIMD-interleaved)
  const int c0 = jl * 64;
  if (tk < TT - 1) {
    // 1024 threads: 8 rows x 128 threads, 4 f32 -> 4 bf16 each
    const int grow = xcc * 128 + jl * 8 + (tid >> 7);
    const int c = (tid & 127) * 4;
    const int idx = inputs[grow * TT + tk + 1];
    f32x4 f0 = *(const f32x4*)(emb + (size_t)idx * EE + c);
    u16x4 oa;
#pragma unroll
    for (int j = 0; j < 4; ++j) oa[j] = f2bf(f0[j]);
    *(u16x4*)(A0 + (size_t)((tk + 1) & 1) * HN0 + (size_t)grow * K0 + c) = oa;
  }
  if (tk < TT) {
    f32x4 acc[2];
#pragma unroll
    for (int n = 0; n < 2; ++n) acc[n] = (f32x4){0.f, 0.f, 0.f, 0.f};
    i32x4 srdA = make_srd(A0 + (size_t)(tk & 1) * HN0);
    const int voA = ((xcc * 128 + rg * 16 + l16) * K0 + q * 8) * 2;
    const u16* gB = Wt0 + (size_t)(c0 / 16) * NK0 * 512;
    if (uselds) {
      if (ch == 0) gemmA<K0>(srdA, voA, ldsb, lane, acc);
      else         gemmB<K0, KTL0>(srdA, voA, ldsb + (size_t)2 * NK0 * 512,
                                   Wt0 + (size_t)(c0 / 16 + 2) * NK0 * 512, lane, acc);
    } else {
      gemmF<K0>(srdA, voA, gB + (size_t)(ch * 2) * NK0 * 512,
                gB + (size_t)(ch * 2 + 1) * NK0 * 512, lane, acc);
    }
    u16* d1 = A1 + (size_t)(tk & 1) * HN1;              // h0' -> layer-1 input (same XCD)
    u16* d2 = A0 + (size_t)((tk + 1) & 1) * HN0 + 512;  // h0 recurrent
#pragma unroll
    for (int n = 0; n < 2; ++n) {
      const int col = c0 + (ch * 2 + n) * 16 + l16;
      const float bs = b0[col];
#pragma unroll
      for (int rr = 0; rr < 4; ++rr) {
        const int grow = xcc * 128 + rg * 16 + q * 4 + rr;
        const u16 v = f2bf(fast_tanh(acc[n][rr] + bs));
        d1[(size_t)grow * K1 + col] = v;
        d2[(size_t)grow * K0 + col] = v;
      }
    }
  }
}

// layer-1 job jl (0..15): h1(tk-1) GEMM
__device__ __forceinline__ void do_l1(int tk, int xcc, int jl, bool uselds,
    const u16* __restrict__ ldsb, const u16* __restrict__ Wt1,
    const float* __restrict__ b1, u16* __restrict__ A1, int tid)
{
  const int lane = tid & 63, wv = tid >> 6, q = lane >> 4, l16 = lane & 15;
  const int ch = (wv >> 2) & 1;
  const int rg = (wv & 3) + ((wv >> 3) << 2);
  const int c0 = jl * 64;
  f32x4 acc[2];
#pragma unroll
  for (int n = 0; n < 2; ++n) acc[n] = (f32x4){0.f, 0.f, 0.f, 0.f};
  i32x4 srdA = make_srd(A1 + (size_t)((tk - 1) & 1) * HN1);
  const int voA = ((xcc * 128 + rg * 16 + l16) * K1 + q * 8) * 2;
  const u16* gB = Wt1 + (size_t)(c0 / 16) * NK1 * 512;
  if (uselds) {
    if (ch == 0) gemmA<K1>(srdA, voA, ldsb, lane, acc);
    else         gemmB<K1, KTL1>(srdA, voA, ldsb + (size_t)2 * NK1 * 512,
                                 Wt1 + (size_t)(c0 / 16 + 2) * NK1 * 512, lane, acc);
  } else {
    gemmF<K1>(srdA, voA, gB + (size_t)(ch * 2) * NK1 * 512,
              gB + (size_t)(ch * 2 + 1) * NK1 * 512, lane, acc);
  }
  u16* d1 = A1 + (size_t)(tk & 1) * HN1 + 1024;         // h1 recurrent
#pragma unroll
  for (int n = 0; n < 2; ++n) {
    const int col = c0 + (ch * 2 + n) * 16 + l16;
    const float bs = b1[col];
#pragma unroll
    for (int rr = 0; rr < 4; ++rr) {
      const int grow = xcc * 128 + rg * 16 + q * 4 + rr;
      d1[(size_t)grow * K1 + col] = f2bf(fast_tanh(acc[n][rr] + bs));
    }
  }
}

__global__ __launch_bounds__(NTHR, 4)
void rnn_kernel(const int* __restrict__ inputs, const float* __restrict__ emb,
    const float* __restrict__ W0, const float* __restrict__ U0, const float* __restrict__ b0,
    const float* __restrict__ W1, const float* __restrict__ U1, const float* __restrict__ b1,
    const float* __restrict__ Wout, const float* __restrict__ bout,
    float* __restrict__ out,
    u16* __restrict__ Wt0, u16* __restrict__ Wt1,
    u16* __restrict__ A0, u16* __restrict__ A1, int* __restrict__ bar)
{
  extern __shared__ u16 lds[];
  int* li = (int*)lds;
  cg::grid_group grid = cg::this_grid();
  const int tid = threadIdx.x, bid = blockIdx.x;

  // ---- startup (grid-distributed): weights, emb(0), zero states + barrier area ----
  const int gstart = bid * NTHR + tid;
  wfill<K0, 512>(Wt0, W0, U0, gstart);
  wfill<K1, 1024>(Wt1, W1, U1, gstart);
  for (int g = gstart; g < BB * EE / 8; g += NBLK * NTHR) {
    const int b = g >> 6, seg = g & 63;
    const int idx = inputs[b * TT];
    const f32x4* s = (const f32x4*)(emb + (size_t)idx * EE + seg * 8);
    f32x4 f0 = s[0], f1 = s[1];
    u16x8 o;
#pragma unroll
    for (int j = 0; j < 4; ++j) { o[j] = f2bf(f0[j]); o[j + 4] = f2bf(f1[j]); }
    *(u16x8*)(A0 + (size_t)b * K0 + seg * 8) = o;
  }
  {
    const u16x8 z = {0, 0, 0, 0, 0, 0, 0, 0};
    for (int g = gstart; g < BB * 1024 / 8; g += NBLK * NTHR) {
      const int b = g >> 7, seg = g & 127;
      *(u16x8*)(A0 + (size_t)b * K0 + 512 + seg * 8) = z;      // h0(-1) = 0
      *(u16x8*)(A1 + (size_t)b * K1 + 1024 + seg * 8) = z;     // h1(-1) = 0
    }
  }
  if (bid == 0) for (int i = tid; i < BAR_INTS; i += NTHR) bar[i] = 0;
  grid.sync();

  // ---- roster: true XCD + slot; second sync publishes per-XCD counts ----
  if (tid == 0) {
    const int xc = __builtin_amdgcn_s_getreg((7 << 11) | 20) & 7;   // HW_REG_XCC_ID
    li[0] = xc;
    li[1] = atomicAdd(&bar[ROSTER_BASE + xc], 1);
  }
  __syncthreads();
  const int xcc = li[0], slot = li[1];
  __syncthreads();
  grid.sync();
  if (tid == 0)
    li[0] = __hip_atomic_load(&bar[ROSTER_BASE + xcc],
                              __ATOMIC_RELAXED, __HIP_MEMORY_SCOPE_AGENT);
  __syncthreads();
  const int nx = li[0];
  __syncthreads();

  // ---- primary job's weights -> LDS: bA (2 frag-cols) + bB kt-prefix (tick-invariant) ----
  if (slot < 32) {
    const bool pL0 = slot < 16;
    const int cb = (pL0 ? slot : slot - 16) * 4;
    const int NKp = pL0 ? NK0 : NK1;
    const int KTLp = pL0 ? KTL0 : KTL1;
    const u16* W = pL0 ? Wt0 : Wt1;
    const u16x8* s = (const u16x8*)(W + (size_t)cb * NKp * 512);
    const int nv = 2 * NKp * 64;
    u16x8* d = (u16x8*)lds;
    for (int i = tid; i < nv; i += NTHR) d[i] = s[i];
    // bB prefix: frag-cols cb+2, cb+3 for kt < KTLp; dest layout (f*KTLp + kt)*512 + lane*8
    u16x8* d2 = d + nv;
    const int nv2 = 2 * KTLp * 64;
    for (int i = tid; i < nv2; i += NTHR) {
      const int f = i / (KTLp * 64);
      const int rem = i - f * (KTLp * 64);
      d2[i] = *((const u16x8*)(W + (size_t)(cb + 2 + f) * NKp * 512) + rem);
    }
  }
  __syncthreads();

  // ---- tick loop: jobs 0..15 = layer0 stripes, 16..31 = layer1 stripes (lagged) ----
  for (int tk = 0; tk <= TT; ++tk) {
    for (int job = slot; job < 32; job += nx) {
      const bool uselds = (job == slot);
      if (job < 16) do_l0(tk, xcc, job, uselds, lds, Wt0, inputs, emb, b0, A0, A1, tid);
      else if (tk >= 1) do_l1(tk, xcc, job - 16, uselds, lds, Wt1, b1, A1, tid);
    }
    xbar(bar, xcc, slot, nx, tk + 1, tid);
  }

  // ---- output (slot 0 per XCD): sigmoid(h1(255) @ Wout + bout) for 128 local rows ----
  if (slot == 0) {
    const int lane = tid & 63, w = tid >> 6;   // first 8 waves x 16 rows
    if (w < 8) {
      i32x4 srdH = make_srd(A1);
      const f32x4* wv = (const f32x4*)(Wout + lane * 16);
      f32x4 w0 = wv[0], w1 = wv[1], w2 = wv[2], w3 = wv[3];
      for (int rr = 0; rr < 16; ++rr) {
        const int grow = xcc * 128 + w * 16 + rr;
        const int vo = (grow * K1 + 1024 + lane * 16) * 2;
        i32x4 hv0 = llvm_amdgcn_raw_buffer_load_i32x4(srdH, vo, 0, AUX_SC0);
        i32x4 hv1 = llvm_amdgcn_raw_buffer_load_i32x4(srdH, vo + 16, 0, AUX_SC0);
        u16x8 lo = __builtin_bit_cast(u16x8, hv0);
        u16x8 hi = __builtin_bit_cast(u16x8, hv1);
        float s = 0.f;
#pragma unroll
        for (int j = 0; j < 4; ++j) {
          s += bf2f(lo[j]) * w0[j];
          s += bf2f(lo[j + 4]) * w1[j];
          s += bf2f(hi[j]) * w2[j];
          s += bf2f(hi[j + 4]) * w3[j];
        }
#pragma unroll
        for (int off = 32; off > 0; off >>= 1) s += __shfl_down(s, off);
        if (lane == 0) out[grow] = 1.f / (1.f + expf(-(s + bout[0])));
      }
    }
  }
}

extern "C" void kernel_launch(void* const* d_in, const int* in_sizes, int n_in,
                              void* d_out, int out_size, void* d_ws, size_t ws_size,
                              hipStream_t stream)
{
  (void)in_sizes; (void)n_in; (void)out_size; (void)ws_size;
  const int*   inputs = (const int*)d_in[0];
  const float* emb    = (const float*)d_in[1];
  const float* W0     = (const float*)d_in[2];
  const float* U0     = (const float*)d_in[3];
  const float* b0     = (const float*)d_in[4];
  const float* W1     = (const float*)d_in[5];
  const float* U1     = (const float*)d_in[6];
  const float* b1     = (const float*)d_in[7];
  const float* Wout   = (const float*)d_in[8];
  const float* bout   = (const float*)d_in[9];
  float* out = (float*)d_out;

  // ws (u16): Wt0 [1024*K0], Wt1 [1024*K1], A0 [2][1024*K0], A1 [2][1024*K1], bar
  u16* Wt0 = (u16*)d_ws;
  u16* Wt1 = Wt0 + (size_t)1024 * K0;
  u16* A0  = Wt1 + (size_t)1024 * K1;
  u16* A1  = A0 + (size_t)2 * 1024 * K0;
  int* bar = (int*)(A1 + (size_t)2 * 1024 * K1);

  static int lds_set = 0;
  if (!lds_set) {
    hipFuncSetAttribute((const void*)rnn_kernel,
                        hipFuncAttributeMaxDynamicSharedMemorySize, LDS_BYTES);
    lds_set = 1;
  }

  void* args[] = { &inputs, &emb, &W0, &U0, &b0, &W1, &U1, &b1, &Wout, &bout,
                   &out, &Wt0, &Wt1, &A0, &A1, &bar };
  hipLaunchCooperativeKernel((void*)rnn_kernel, dim3(NBLK), dim3(NTHR), args, LDS_BYTES, stream);
}

// Round 10
// 7709.816 us; speedup vs baseline: 1.2263x; 1.2263x over previous
//
#include <hip/hip_runtime.h>
#include <hip/hip_cooperative_groups.h>
#include <math.h>

namespace cg = cooperative_groups;

typedef unsigned short u16;
typedef __bf16 bf16x8 __attribute__((ext_vector_type(8)));
typedef float f32x4 __attribute__((ext_vector_type(4)));
typedef unsigned short u16x8 __attribute__((ext_vector_type(8)));
typedef int i32x4 __attribute__((ext_vector_type(4)));

#define NBLK 256
#define NTHR 512         // 8 waves, row-split: 2 waves/SIMD (r9 proved 4/SIMD is net-negative)
#define BB 1024
#define TT 256
#define EE 512
#define UU 1024
#define K0 1536          // A0 row: [emb(512) | h0(1024)]
#define K1 2048          // A1 row: [h0'(1024) | h1(1024)]
#define NK0 48           // K0/32
#define NK1 64           // K1/32
#define KTL0 32          // L0: bB kt-prefix resident in LDS (of 48)
#define KTL1 16          // L1: bB kt-prefix resident in LDS (of 64)
#define HN0 ((size_t)BB * K0)
#define HN1 ((size_t)BB * K1)
// LDS: bA 2 frag-cols (L0 96KB / L1 128KB) + bB prefix (L0 64KB / L1 32KB) = 160KB
#define LDS_BYTES 163840

// bar layout (ints)
#define ROSTER_BASE 0            // [0..7] per-XCD block count
#define FLAG_BASE 32             // 8 * 256 arrival flags
#define EPOCH_BASE (32 + 2048)   // 8 epochs, 32-int stride
#define BAR_INTS 2560

#define AUX_SC0 1        // bypass L1, served by local L2 (A stream: no L1 reuse)
#define AUX_L1  0        // weights: keep L1 (8 waves/CU share the same lines)

__device__ i32x4 llvm_amdgcn_raw_buffer_load_i32x4(i32x4 srsrc, int voffset, int soffset,
                                                   int aux) __asm("llvm.amdgcn.raw.buffer.load.v4i32");

__device__ __forceinline__ i32x4 make_srd(const void* p) {
  union { const void* p; int i[2]; } u; u.p = p;
  i32x4 r; r.x = u.i[0]; r.y = u.i[1]; r.z = -1; r.w = 0x00020000;
  return r;
}

__device__ __forceinline__ u16 f2bf(float f) {
  unsigned u = __builtin_bit_cast(unsigned, f);
  u += 0x7fffu + ((u >> 16) & 1u);
  return (u16)(u >> 16);
}
__device__ __forceinline__ float bf2f(u16 h) {
  return __builtin_bit_cast(float, ((unsigned)h) << 16);
}
__device__ __forceinline__ float fast_tanh(float x) {
  x = fminf(fmaxf(x, -15.f), 15.f);
  float e = __expf(2.f * x);
  return (e - 1.f) / (e + 1.f);
}

// weight transpose + MFMA-fragment swizzle (r2/r3-verified layout):
// elem g = (cb*NK + kt)*64 + lane (8 u16 each); value = Wfull[k][n],
// n = cb*16 + (lane&15), k = kt*32 + (lane>>4)*8 + e
template<int K, int KLOW>
__device__ __forceinline__ void wfill(u16* __restrict__ Wt,
    const float* __restrict__ Wl, const float* __restrict__ Wh, int gstart) {
  constexpr int NK = K / 32;
  constexpr int NG = 1024 * K / 8;
  for (int g = gstart; g < NG; g += NBLK * NTHR) {
    const int lane = g & 63;
    const int r = g >> 6;
    const int kt = r % NK;
    const int cb = r / NK;
    const int n = cb * 16 + (lane & 15);
    const int kb = kt * 32 + (lane >> 4) * 8;
    u16x8 o;
#pragma unroll
    for (int e = 0; e < 8; ++e) {
      const int k = kb + e;
      const float v = (k < KLOW) ? Wl[(size_t)k * UU + n] : Wh[(size_t)(k - KLOW) * UU + n];
      o[e] = f2bf(v);
    }
    *(u16x8*)(Wt + (size_t)g * 8) = o;
  }
}

// XCD-local barrier: agent-scope flags + leader + epoch; guarded polls bail instead of hanging.
__device__ __forceinline__ void xbar(int* __restrict__ bar, int xcc, int slot, int nx,
                                     int tgt, int tid) {
  __syncthreads();   // all waves' stores drained before arrival
  if (tid < 64) {
    if (tid == 0)
      __hip_atomic_store(&bar[FLAG_BASE + xcc * 256 + slot], tgt,
                         __ATOMIC_RELAXED, __HIP_MEMORY_SCOPE_AGENT);
    if (slot == 0) {
      for (int base = 0; base < nx; base += 64) {
        const int i = base + tid;
        const bool act = (i < nx);
        int guard = 0;
        bool done = false;
        do {
          int v = act ? __hip_atomic_load(&bar[FLAG_BASE + xcc * 256 + i],
                                          __ATOMIC_RELAXED, __HIP_MEMORY_SCOPE_AGENT)
                      : tgt;
          done = __all(v >= tgt) != 0;
        } while (!done && ++guard < 300000);
      }
      if (tid == 0)
        __hip_atomic_store(&bar[EPOCH_BASE + xcc * 32], tgt,
                           __ATOMIC_RELAXED, __HIP_MEMORY_SCOPE_AGENT);
    } else if (tid == 0) {
      int guard = 0;
      while (__hip_atomic_load(&bar[EPOCH_BASE + xcc * 32],
                               __ATOMIC_RELAXED, __HIP_MEMORY_SCOPE_AGENT) < tgt
             && ++guard < 600000)
        __builtin_amdgcn_s_sleep(8);
    }
  }
  __syncthreads();
}

// 4 MFMA for one kt: b0/b1 from LDS pointers, b2/b3 from LDS-or-global pointers
__device__ __forceinline__ void mf1(const i32x4& av,
    const u16* __restrict__ p0, const u16* __restrict__ p1,
    const u16* __restrict__ q2, const u16* __restrict__ q3,
    size_t koff, int lo, f32x4 (&acc)[4]) {
  u16x8 b0 = *(const u16x8*)(p0 + koff + lo);
  u16x8 b1 = *(const u16x8*)(p1 + koff + lo);
  u16x8 b2 = *(const u16x8*)(q2 + koff + lo);
  u16x8 b3 = *(const u16x8*)(q3 + koff + lo);
  bf16x8 fa0 = __builtin_bit_cast(bf16x8, av);
  bf16x8 fb0 = __builtin_bit_cast(bf16x8, b0);
  bf16x8 fb1 = __builtin_bit_cast(bf16x8, b1);
  bf16x8 fb2 = __builtin_bit_cast(bf16x8, b2);
  bf16x8 fb3 = __builtin_bit_cast(bf16x8, b3);
  acc[0] = __builtin_amdgcn_mfma_f32_16x16x32_bf16(fa0, fb0, acc[0], 0, 0, 0);
  acc[1] = __builtin_amdgcn_mfma_f32_16x16x32_bf16(fa0, fb1, acc[1], 0, 0, 0);
  acc[2] = __builtin_amdgcn_mfma_f32_16x16x32_bf16(fa0, fb2, acc[2], 0, 0, 0);
  acc[3] = __builtin_amdgcn_mfma_f32_16x16x32_bf16(fa0, fb3, acc[3], 0, 0, 0);
}

// 4 MFMA for one kt: b0/b1 from LDS, b2/b3 from pre-loaded REGISTERS (suffix path)
__device__ __forceinline__ void mf1r(const i32x4& av,
    const u16* __restrict__ p0, const u16* __restrict__ p1,
    size_t koff, int lo, const i32x4& b2v, const i32x4& b3v, f32x4 (&acc)[4]) {
  u16x8 b0 = *(const u16x8*)(p0 + koff + lo);
  u16x8 b1 = *(const u16x8*)(p1 + koff + lo);
  bf16x8 fa0 = __builtin_bit_cast(bf16x8, av);
  bf16x8 fb0 = __builtin_bit_cast(bf16x8, b0);
  bf16x8 fb1 = __builtin_bit_cast(bf16x8, b1);
  bf16x8 fb2 = __builtin_bit_cast(bf16x8, b2v);
  bf16x8 fb3 = __builtin_bit_cast(bf16x8, b3v);
  acc[0] = __builtin_amdgcn_mfma_f32_16x16x32_bf16(fa0, fb0, acc[0], 0, 0, 0);
  acc[1] = __builtin_amdgcn_mfma_f32_16x16x32_bf16(fa0, fb1, acc[1], 0, 0, 0);
  acc[2] = __builtin_amdgcn_mfma_f32_16x16x32_bf16(fa0, fb2, acc[2], 0, 0, 0);
  acc[3] = __builtin_amdgcn_mfma_f32_16x16x32_bf16(fa0, fb3, acc[3], 0, 0, 0);
}

// C[128x64] += A[128xK] @ B[Kx64] (per wave: 16 rows).
// Prefix (kt<KTL): B all from LDS; A batched in 8-kt double-buffered groups.
// Suffix (kt>=KTL): {4 A + 8 B} groups, THREE-deep rotation (prefetch 2 groups
// ahead; groups 0,1 issued during the last two prefix groups) -> each group's
// loads get ~2 group-compute times (~300-400cy) of cover instead of ~150.
// sched_barrier(0) pins issue order (r8-proven, -12%).
template<int K, int KTL>
__device__ __forceinline__ void gemm2(const i32x4& srdA, int voA,
    const u16* __restrict__ bA, const u16* __restrict__ bB,
    const u16* __restrict__ bP, int lane, f32x4 (&acc)[4]) {
  constexpr int NK = K / 32;
  const int lo = lane * 8;

  if constexpr (KTL == 0) {
    // degraded-mode fallback (nx<32 only): simple r4-style loop
    const u16* p0 = bA;
    const u16* p1 = bA + (size_t)NK * 512;
    const u16* q2 = bB;
    const u16* q3 = bB + (size_t)NK * 512;
#pragma unroll 8
    for (int kt = 0; kt < NK; ++kt) {
      i32x4 a0 = llvm_amdgcn_raw_buffer_load_i32x4(srdA, voA + kt * 64, 0, AUX_SC0);
      mf1(a0, p0, p1, q2, q3, (size_t)kt * 512, lo, acc);
    }
  } else {
    constexpr int NGP = KTL / 8;          // prefix groups of 8 (KTL0=32->4, KTL1=16->2)
    constexpr int NGS = (NK - KTL) / 4;   // suffix groups of 4 (L0: 4, L1: 12)
    const u16* p0 = bA;
    const u16* p1 = bA + (size_t)NK * 512;
    const u16* bP3 = bP + (size_t)KTL * 512;
    i32x4 srdB = make_srd(bB);
    const int lob = lane * 16;            // byte offset of this lane's 16B in a kt-slice

    i32x4 aE[8], aO[8];
    i32x4 sA0[4], sB0[8], sA1[4], sB1[8], sA2[4], sB2[8];

#pragma unroll
    for (int j = 0; j < 8; ++j)
      aE[j] = llvm_amdgcn_raw_buffer_load_i32x4(srdA, voA + j * 64, 0, AUX_SC0);

#pragma unroll
    for (int g = 0; g < NGP; ++g) {
      if (g + 1 < NGP) {
#pragma unroll
        for (int j = 0; j < 8; ++j) {
          i32x4 v = llvm_amdgcn_raw_buffer_load_i32x4(srdA, voA + ((g + 1) * 8 + j) * 64, 0, AUX_SC0);
          if ((g & 1) == 0) aO[j] = v; else aE[j] = v;
        }
      }
      if (g == NGP - 2) {
        // suffix group 0 -> buffer 0
#pragma unroll
        for (int j = 0; j < 4; ++j) {
          sA0[j] = llvm_amdgcn_raw_buffer_load_i32x4(srdA, voA + (KTL + j) * 64, 0, AUX_SC0);
          sB0[2 * j]     = llvm_amdgcn_raw_buffer_load_i32x4(srdB, (0 * NK + KTL + j) * 1024 + lob, 0, AUX_L1);
          sB0[2 * j + 1] = llvm_amdgcn_raw_buffer_load_i32x4(srdB, (1 * NK + KTL + j) * 1024 + lob, 0, AUX_L1);
        }
      }
      if (g == NGP - 1) {
        // suffix group 1 -> buffer 1
#pragma unroll
        for (int j = 0; j < 4; ++j) {
          sA1[j] = llvm_amdgcn_raw_buffer_load_i32x4(srdA, voA + (KTL + 4 + j) * 64, 0, AUX_SC0);
          sB1[2 * j]     = llvm_amdgcn_raw_buffer_load_i32x4(srdB, (0 * NK + KTL + 4 + j) * 1024 + lob, 0, AUX_L1);
          sB1[2 * j + 1] = llvm_amdgcn_raw_buffer_load_i32x4(srdB, (1 * NK + KTL + 4 + j) * 1024 + lob, 0, AUX_L1);
        }
      }
      __builtin_amdgcn_sched_barrier(0);   // pin: loads above, compute below
#pragma unroll
      for (int j = 0; j < 8; ++j) {
        const int kt = g * 8 + j;
        if ((g & 1) == 0) mf1(aE[j], p0, p1, bP, bP3, (size_t)kt * 512, lo, acc);
        else              mf1(aO[j], p0, p1, bP, bP3, (size_t)kt * 512, lo, acc);
      }
      __builtin_amdgcn_sched_barrier(0);   // pin: this group's compute before next issue
    }

#pragma unroll
    for (int s = 0; s < NGS; ++s) {
      if (s + 2 < NGS) {
        const int kb = KTL + (s + 2) * 4;
        const int m = (s + 2) % 3;          // target buffer (consumed at s-1: WAR-safe)
#pragma unroll
        for (int j = 0; j < 4; ++j) {
          i32x4 va = llvm_amdgcn_raw_buffer_load_i32x4(srdA, voA + (kb + j) * 64, 0, AUX_SC0);
          i32x4 v0 = llvm_amdgcn_raw_buffer_load_i32x4(srdB, (0 * NK + kb + j) * 1024 + lob, 0, AUX_L1);
          i32x4 v1 = llvm_amdgcn_raw_buffer_load_i32x4(srdB, (1 * NK + kb + j) * 1024 + lob, 0, AUX_L1);
          if (m == 0)      { sA0[j] = va; sB0[2 * j] = v0; sB0[2 * j + 1] = v1; }
          else if (m == 1) { sA1[j] = va; sB1[2 * j] = v0; sB1[2 * j + 1] = v1; }
          else             { sA2[j] = va; sB2[2 * j] = v0; sB2[2 * j + 1] = v1; }
        }
      }
      __builtin_amdgcn_sched_barrier(0);   // pin: loads above, compute below
      {
        const int mc = s % 3;
#pragma unroll
        for (int j = 0; j < 4; ++j) {
          const int kt = KTL + s * 4 + j;
          if (mc == 0)      mf1r(sA0[j], p0, p1, (size_t)kt * 512, lo, sB0[2 * j], sB0[2 * j + 1], acc);
          else if (mc == 1) mf1r(sA1[j], p0, p1, (size_t)kt * 512, lo, sB1[2 * j], sB1[2 * j + 1], acc);
          else              mf1r(sA2[j], p0, p1, (size_t)kt * 512, lo, sB2[2 * j], sB2[2 * j + 1], acc);
        }
      }
      __builtin_amdgcn_sched_barrier(0);   // pin: compute before next group's issue
    }
  }
}

// layer-0 job jl (0..15): stage emb(tk+1) for rows jl*8..+8, then h0'(tk) GEMM
__device__ __forceinline__ void do_l0(int tk, int xcc, int jl, bool uselds,
    const u16* __restrict__ ldsb, const u16* __restrict__ Wt0,
    const int* __restrict__ inputs, const float* __restrict__ emb,
    const float* __restrict__ b0, u16* __restrict__ A0, u16* __restrict__ A1,
    int tid)
{
  const int lane = tid & 63, w = tid >> 6, q = lane >> 4, l16 = lane & 15;
  const int c0 = jl * 64;
  if (tk < TT - 1) {
    // 512 threads: 8 rows x 64 threads, 8 f32 -> 8 bf16 each
    const int grow = xcc * 128 + jl * 8 + (tid >> 6);
    const int c = (tid & 63) * 8;
    const int idx = inputs[grow * TT + tk + 1];
    const f32x4* s = (const f32x4*)(emb + (size_t)idx * EE + c);
    f32x4 f0 = s[0], f1 = s[1];
    u16x8 oa;
#pragma unroll
    for (int j = 0; j < 4; ++j) { oa[j] = f2bf(f0[j]); oa[j + 4] = f2bf(f1[j]); }
    *(u16x8*)(A0 + (size_t)((tk + 1) & 1) * HN0 + (size_t)grow * K0 + c) = oa;
  }
  if (tk < TT) {
    f32x4 acc[4];
#pragma unroll
    for (int n = 0; n < 4; ++n) acc[n] = (f32x4){0.f, 0.f, 0.f, 0.f};
    i32x4 srdA = make_srd(A0 + (size_t)(tk & 1) * HN0);
    const int voA = ((xcc * 128 + w * 16 + l16) * K0 + q * 8) * 2;
    const u16* gA = Wt0 + (size_t)(c0 / 16) * NK0 * 512;
    const u16* bB = Wt0 + (size_t)(c0 / 16 + 2) * NK0 * 512;
    if (uselds) gemm2<K0, KTL0>(srdA, voA, ldsb, bB,
                                ldsb + (size_t)2 * NK0 * 512, lane, acc);
    else        gemm2<K0, 0   >(srdA, voA, gA, bB, ldsb, lane, acc);
    u16* d1 = A1 + (size_t)(tk & 1) * HN1;              // h0' -> layer-1 input (same XCD)
    u16* d2 = A0 + (size_t)((tk + 1) & 1) * HN0 + 512;  // h0 recurrent
#pragma unroll
    for (int n = 0; n < 4; ++n) {
      const int col = c0 + n * 16 + l16;
      const float bs = b0[col];
#pragma unroll
      for (int rr = 0; rr < 4; ++rr) {
        const int grow = xcc * 128 + w * 16 + q * 4 + rr;
        const u16 v = f2bf(fast_tanh(acc[n][rr] + bs));
        d1[(size_t)grow * K1 + col] = v;
        d2[(size_t)grow * K0 + col] = v;
      }
    }
  }
}

// layer-1 job jl (0..15): h1(tk-1) GEMM
__device__ __forceinline__ void do_l1(int tk, int xcc, int jl, bool uselds,
    const u16* __restrict__ ldsb, const u16* __restrict__ Wt1,
    const float* __restrict__ b1, u16* __restrict__ A1, int tid)
{
  const int lane = tid & 63, w = tid >> 6, q = lane >> 4, l16 = lane & 15;
  const int c0 = jl * 64;
  f32x4 acc[4];
#pragma unroll
  for (int n = 0; n < 4; ++n) acc[n] = (f32x4){0.f, 0.f, 0.f, 0.f};
  i32x4 srdA = make_srd(A1 + (size_t)((tk - 1) & 1) * HN1);
  const int voA = ((xcc * 128 + w * 16 + l16) * K1 + q * 8) * 2;
  const u16* gA = Wt1 + (size_t)(c0 / 16) * NK1 * 512;
  const u16* bB = Wt1 + (size_t)(c0 / 16 + 2) * NK1 * 512;
  if (uselds) gemm2<K1, KTL1>(srdA, voA, ldsb, bB,
                              ldsb + (size_t)2 * NK1 * 512, lane, acc);
  else        gemm2<K1, 0   >(srdA, voA, gA, bB, ldsb, lane, acc);
  u16* d1 = A1 + (size_t)(tk & 1) * HN1 + 1024;         // h1 recurrent
#pragma unroll
  for (int n = 0; n < 4; ++n) {
    const int col = c0 + n * 16 + l16;
    const float bs = b1[col];
#pragma unroll
    for (int rr = 0; rr < 4; ++rr) {
      const int grow = xcc * 128 + w * 16 + q * 4 + rr;
      d1[(size_t)grow * K1 + col] = f2bf(fast_tanh(acc[n][rr] + bs));
    }
  }
}

__global__ __launch_bounds__(NTHR, 2)
void rnn_kernel(const int* __restrict__ inputs, const float* __restrict__ emb,
    const float* __restrict__ W0, const float* __restrict__ U0, const float* __restrict__ b0,
    const float* __restrict__ W1, const float* __restrict__ U1, const float* __restrict__ b1,
    const float* __restrict__ Wout, const float* __restrict__ bout,
    float* __restrict__ out,
    u16* __restrict__ Wt0, u16* __restrict__ Wt1,
    u16* __restrict__ A0, u16* __restrict__ A1, int* __restrict__ bar)
{
  extern __shared__ u16 lds[];
  int* li = (int*)lds;
  cg::grid_group grid = cg::this_grid();
  const int tid = threadIdx.x, bid = blockIdx.x;

  // ---- startup (grid-distributed): weights, emb(0), zero states + barrier area ----
  const int gstart = bid * NTHR + tid;
  wfill<K0, 512>(Wt0, W0, U0, gstart);
  wfill<K1, 1024>(Wt1, W1, U1, gstart);
  for (int g = gstart; g < BB * EE / 8; g += NBLK * NTHR) {
    const int b = g >> 6, seg = g & 63;
    const int idx = inputs[b * TT];
    const f32x4* s = (const f32x4*)(emb + (size_t)idx * EE + seg * 8);
    f32x4 f0 = s[0], f1 = s[1];
    u16x8 o;
#pragma unroll
    for (int j = 0; j < 4; ++j) { o[j] = f2bf(f0[j]); o[j + 4] = f2bf(f1[j]); }
    *(u16x8*)(A0 + (size_t)b * K0 + seg * 8) = o;
  }
  {
    const u16x8 z = {0, 0, 0, 0, 0, 0, 0, 0};
    for (int g = gstart; g < BB * 1024 / 8; g += NBLK * NTHR) {
      const int b = g >> 7, seg = g & 127;
      *(u16x8*)(A0 + (size_t)b * K0 + 512 + seg * 8) = z;      // h0(-1) = 0
      *(u16x8*)(A1 + (size_t)b * K1 + 1024 + seg * 8) = z;     // h1(-1) = 0
    }
  }
  if (bid == 0) for (int i = tid; i < BAR_INTS; i += NTHR) bar[i] = 0;
  grid.sync();

  // ---- roster: true XCD + slot; second sync publishes per-XCD counts ----
  if (tid == 0) {
    const int xc = __builtin_amdgcn_s_getreg((7 << 11) | 20) & 7;   // HW_REG_XCC_ID
    li[0] = xc;
    li[1] = atomicAdd(&bar[ROSTER_BASE + xc], 1);
  }
  __syncthreads();
  const int xcc = li[0], slot = li[1];
  __syncthreads();
  grid.sync();
  if (tid == 0)
    li[0] = __hip_atomic_load(&bar[ROSTER_BASE + xcc],
                              __ATOMIC_RELAXED, __HIP_MEMORY_SCOPE_AGENT);
  __syncthreads();
  const int nx = li[0];
  __syncthreads();

  // ---- primary job's weights -> LDS: bA (2 frag-cols) + bB kt-prefix (tick-invariant) ----
  if (slot < 32) {
    const bool pL0 = slot < 16;
    const int cb = (pL0 ? slot : slot - 16) * 4;
    const int NKp = pL0 ? NK0 : NK1;
    const int KTLp = pL0 ? KTL0 : KTL1;
    const u16* W = pL0 ? Wt0 : Wt1;
    const u16x8* s = (const u16x8*)(W + (size_t)cb * NKp * 512);
    const int nv = 2 * NKp * 64;
    u16x8* d = (u16x8*)lds;
    for (int i = tid; i < nv; i += NTHR) d[i] = s[i];
    // bB prefix: frag-cols cb+2, cb+3 for kt < KTLp; dest layout (f*KTLp + kt)*512 + lane*8
    u16x8* d2 = d + nv;
    const int nv2 = 2 * KTLp * 64;
    for (int i = tid; i < nv2; i += NTHR) {
      const int f = i / (KTLp * 64);
      const int rem = i - f * (KTLp * 64);
      d2[i] = *((const u16x8*)(W + (size_t)(cb + 2 + f) * NKp * 512) + rem);
    }
  }
  __syncthreads();

  // ---- tick loop: jobs 0..15 = layer0 stripes, 16..31 = layer1 stripes (lagged) ----
  for (int tk = 0; tk <= TT; ++tk) {
    for (int job = slot; job < 32; job += nx) {
      const bool uselds = (job == slot);
      if (job < 16) do_l0(tk, xcc, job, uselds, lds, Wt0, inputs, emb, b0, A0, A1, tid);
      else if (tk >= 1) do_l1(tk, xcc, job - 16, uselds, lds, Wt1, b1, A1, tid);
    }
    xbar(bar, xcc, slot, nx, tk + 1, tid);
  }

  // ---- output (slot 0 per XCD): sigmoid(h1(255) @ Wout + bout) for 128 local rows ----
  if (slot == 0) {
    const int lane = tid & 63, w = tid >> 6;   // 8 waves x 16 rows
    i32x4 srdH = make_srd(A1);
    const f32x4* wv = (const f32x4*)(Wout + lane * 16);
    f32x4 w0 = wv[0], w1 = wv[1], w2 = wv[2], w3 = wv[3];
    for (int rr = 0; rr < 16; ++rr) {
      const int grow = xcc * 128 + w * 16 + rr;
      const int vo = (grow * K1 + 1024 + lane * 16) * 2;
      i32x4 hv0 = llvm_amdgcn_raw_buffer_load_i32x4(srdH, vo, 0, AUX_SC0);
      i32x4 hv1 = llvm_amdgcn_raw_buffer_load_i32x4(srdH, vo + 16, 0, AUX_SC0);
      u16x8 lo = __builtin_bit_cast(u16x8, hv0);
      u16x8 hi = __builtin_bit_cast(u16x8, hv1);
      float s = 0.f;
#pragma unroll
      for (int j = 0; j < 4; ++j) {
        s += bf2f(lo[j]) * w0[j];
        s += bf2f(lo[j + 4]) * w1[j];
        s += bf2f(hi[j]) * w2[j];
        s += bf2f(hi[j + 4]) * w3[j];
      }
#pragma unroll
      for (int off = 32; off > 0; off >>= 1) s += __shfl_down(s, off);
      if (lane == 0) out[grow] = 1.f / (1.f + expf(-(s + bout[0])));
    }
  }
}

extern "C" void kernel_launch(void* const* d_in, const int* in_sizes, int n_in,
                              void* d_out, int out_size, void* d_ws, size_t ws_size,
                              hipStream_t stream)
{
  (void)in_sizes; (void)n_in; (void)out_size; (void)ws_size;
  const int*   inputs = (const int*)d_in[0];
  const float* emb    = (const float*)d_in[1];
  const float* W0     = (const float*)d_in[2];
  const float* U0     = (const float*)d_in[3];
  const float* b0     = (const float*)d_in[4];
  const float* W1     = (const float*)d_in[5];
  const float* U1     = (const float*)d_in[6];
  const float* b1     = (const float*)d_in[7];
  const float* Wout   = (const float*)d_in[8];
  const float* bout   = (const float*)d_in[9];
  float* out = (float*)d_out;

  // ws (u16): Wt0 [1024*K0], Wt1 [1024*K1], A0 [2][1024*K0], A1 [2][1024*K1], bar
  u16* Wt0 = (u16*)d_ws;
  u16* Wt1 = Wt0 + (size_t)1024 * K0;
  u16* A0  = Wt1 + (size_t)1024 * K1;
  u16* A1  = A0 + (size_t)2 * 1024 * K0;
  int* bar = (int*)(A1 + (size_t)2 * 1024 * K1);

  static int lds_set = 0;
  if (!lds_set) {
    hipFuncSetAttribute((const void*)rnn_kernel,
                        hipFuncAttributeMaxDynamicSharedMemorySize, LDS_BYTES);
    lds_set = 1;
  }

  void* args[] = { &inputs, &emb, &W0, &U0, &b0, &W1, &U1, &b1, &Wout, &bout,
                   &out, &Wt0, &Wt1, &A0, &A1, &bar };
  hipLaunchCooperativeKernel((void*)rnn_kernel, dim3(NBLK), dim3(NTHR), args, LDS_BYTES, stream);
}

// Round 11
// 5976.264 us; speedup vs baseline: 1.5820x; 1.2901x over previous
//
#include <hip/hip_runtime.h>
#include <hip/hip_cooperative_groups.h>
#include <math.h>

namespace cg = cooperative_groups;

typedef unsigned short u16;
typedef __bf16 bf16x8 __attribute__((ext_vector_type(8)));
typedef float f32x4 __attribute__((ext_vector_type(4)));
typedef unsigned short u16x8 __attribute__((ext_vector_type(8)));
typedef int i32x4 __attribute__((ext_vector_type(4)));

#define NBLK 256
#define NTHR 512         // 8 waves, row-split: 2 waves/SIMD (r9: 4/SIMD net-negative; r10: depth-3 net-negative)
#define BB 1024
#define TT 256
#define EE 512
#define UU 1024
#define K0 1536          // A0 row: [emb(512) | h0(1024)]
#define K1 2048          // A1 row: [h0'(1024) | h1(1024)]
#define NK0 48           // K0/32
#define NK1 64           // K1/32
#define KTL0 32          // L0: bB kt-prefix resident in LDS (of 48)
#define KTL1 16          // L1: bB kt-prefix resident in LDS (of 64)
#define HN0 ((size_t)BB * K0)
#define HN1 ((size_t)BB * K1)
// LDS: bA 2 frag-cols (L0 96KB / L1 128KB) + bB prefix (L0 64KB / L1 32KB) = 160KB
#define LDS_BYTES 163840

// bar layout (ints)
#define ROSTER_BASE 0            // [0..7] per-XCD block count
#define FLAG_BASE 32             // 8 * 256 arrival flags
#define EPOCH_BASE (32 + 2048)   // 8 epochs, 32-int stride
#define BAR_INTS 2560

#define AUX_SC0 1        // bypass L1, served by local L2 (A stream: no L1 reuse)
#define AUX_L1  0        // weights: keep L1 (8 waves/CU share the same lines)

__device__ i32x4 llvm_amdgcn_raw_buffer_load_i32x4(i32x4 srsrc, int voffset, int soffset,
                                                   int aux) __asm("llvm.amdgcn.raw.buffer.load.v4i32");

__device__ __forceinline__ i32x4 make_srd(const void* p) {
  union { const void* p; int i[2]; } u; u.p = p;
  i32x4 r; r.x = u.i[0]; r.y = u.i[1]; r.z = -1; r.w = 0x00020000;
  return r;
}

__device__ __forceinline__ u16 f2bf(float f) {
  unsigned u = __builtin_bit_cast(unsigned, f);
  u += 0x7fffu + ((u >> 16) & 1u);
  return (u16)(u >> 16);
}
__device__ __forceinline__ float bf2f(u16 h) {
  return __builtin_bit_cast(float, ((unsigned)h) << 16);
}
__device__ __forceinline__ float fast_tanh(float x) {
  x = fminf(fmaxf(x, -15.f), 15.f);
  float e = __expf(2.f * x);
  return (e - 1.f) / (e + 1.f);
}

// weight transpose + MFMA-fragment swizzle (r2/r3-verified layout):
// elem g = (cb*NK + kt)*64 + lane (8 u16 each); value = Wfull[k][n],
// n = cb*16 + (lane&15), k = kt*32 + (lane>>4)*8 + e
template<int K, int KLOW>
__device__ __forceinline__ void wfill(u16* __restrict__ Wt,
    const float* __restrict__ Wl, const float* __restrict__ Wh, int gstart) {
  constexpr int NK = K / 32;
  constexpr int NG = 1024 * K / 8;
  for (int g = gstart; g < NG; g += NBLK * NTHR) {
    const int lane = g & 63;
    const int r = g >> 6;
    const int kt = r % NK;
    const int cb = r / NK;
    const int n = cb * 16 + (lane & 15);
    const int kb = kt * 32 + (lane >> 4) * 8;
    u16x8 o;
#pragma unroll
    for (int e = 0; e < 8; ++e) {
      const int k = kb + e;
      const float v = (k < KLOW) ? Wl[(size_t)k * UU + n] : Wh[(size_t)(k - KLOW) * UU + n];
      o[e] = f2bf(v);
    }
    *(u16x8*)(Wt + (size_t)g * 8) = o;
  }
}

// XCD-local barrier: agent-scope flags + leader + epoch; guarded polls bail instead of hanging.
__device__ __forceinline__ void xbar(int* __restrict__ bar, int xcc, int slot, int nx,
                                     int tgt, int tid) {
  __syncthreads();   // all waves' stores drained before arrival
  if (tid < 64) {
    if (tid == 0)
      __hip_atomic_store(&bar[FLAG_BASE + xcc * 256 + slot], tgt,
                         __ATOMIC_RELAXED, __HIP_MEMORY_SCOPE_AGENT);
    if (slot == 0) {
      for (int base = 0; base < nx; base += 64) {
        const int i = base + tid;
        const bool act = (i < nx);
        int guard = 0;
        bool done = false;
        do {
          int v = act ? __hip_atomic_load(&bar[FLAG_BASE + xcc * 256 + i],
                                          __ATOMIC_RELAXED, __HIP_MEMORY_SCOPE_AGENT)
                      : tgt;
          done = __all(v >= tgt) != 0;
        } while (!done && ++guard < 300000);
      }
      if (tid == 0)
        __hip_atomic_store(&bar[EPOCH_BASE + xcc * 32], tgt,
                           __ATOMIC_RELAXED, __HIP_MEMORY_SCOPE_AGENT);
    } else if (tid == 0) {
      int guard = 0;
      while (__hip_atomic_load(&bar[EPOCH_BASE + xcc * 32],
                               __ATOMIC_RELAXED, __HIP_MEMORY_SCOPE_AGENT) < tgt
             && ++guard < 600000)
        __builtin_amdgcn_s_sleep(8);
    }
  }
  __syncthreads();
}

// 4 MFMA for one kt: b0/b1 from LDS pointers, b2/b3 from LDS-or-global pointers
__device__ __forceinline__ void mf1(const i32x4& av,
    const u16* __restrict__ p0, const u16* __restrict__ p1,
    const u16* __restrict__ q2, const u16* __restrict__ q3,
    size_t koff, int lo, f32x4 (&acc)[4]) {
  u16x8 b0 = *(const u16x8*)(p0 + koff + lo);
  u16x8 b1 = *(const u16x8*)(p1 + koff + lo);
  u16x8 b2 = *(const u16x8*)(q2 + koff + lo);
  u16x8 b3 = *(const u16x8*)(q3 + koff + lo);
  bf16x8 fa0 = __builtin_bit_cast(bf16x8, av);
  bf16x8 fb0 = __builtin_bit_cast(bf16x8, b0);
  bf16x8 fb1 = __builtin_bit_cast(bf16x8, b1);
  bf16x8 fb2 = __builtin_bit_cast(bf16x8, b2);
  bf16x8 fb3 = __builtin_bit_cast(bf16x8, b3);
  acc[0] = __builtin_amdgcn_mfma_f32_16x16x32_bf16(fa0, fb0, acc[0], 0, 0, 0);
  acc[1] = __builtin_amdgcn_mfma_f32_16x16x32_bf16(fa0, fb1, acc[1], 0, 0, 0);
  acc[2] = __builtin_amdgcn_mfma_f32_16x16x32_bf16(fa0, fb2, acc[2], 0, 0, 0);
  acc[3] = __builtin_amdgcn_mfma_f32_16x16x32_bf16(fa0, fb3, acc[3], 0, 0, 0);
}

// 4 MFMA for one kt: b0/b1 from LDS, b2/b3 from pre-loaded REGISTERS (suffix path)
__device__ __forceinline__ void mf1r(const i32x4& av,
    const u16* __restrict__ p0, const u16* __restrict__ p1,
    size_t koff, int lo, const i32x4& b2v, const i32x4& b3v, f32x4 (&acc)[4]) {
  u16x8 b0 = *(const u16x8*)(p0 + koff + lo);
  u16x8 b1 = *(const u16x8*)(p1 + koff + lo);
  bf16x8 fa0 = __builtin_bit_cast(bf16x8, av);
  bf16x8 fb0 = __builtin_bit_cast(bf16x8, b0);
  bf16x8 fb1 = __builtin_bit_cast(bf16x8, b1);
  bf16x8 fb2 = __builtin_bit_cast(bf16x8, b2v);
  bf16x8 fb3 = __builtin_bit_cast(bf16x8, b3v);
  acc[0] = __builtin_amdgcn_mfma_f32_16x16x32_bf16(fa0, fb0, acc[0], 0, 0, 0);
  acc[1] = __builtin_amdgcn_mfma_f32_16x16x32_bf16(fa0, fb1, acc[1], 0, 0, 0);
  acc[2] = __builtin_amdgcn_mfma_f32_16x16x32_bf16(fa0, fb2, acc[2], 0, 0, 0);
  acc[3] = __builtin_amdgcn_mfma_f32_16x16x32_bf16(fa0, fb3, acc[3], 0, 0, 0);
}

// C[128x64] += A[128xK] @ B[Kx64] (per wave: 16 rows). r8-proven structure:
// prefix 8-kt double-buffered A groups (B from LDS); suffix 4-kt double-buffered
// {4A+8B} groups; sched_barrier(0) pins issue order (-12%, r8).
// NEW (r11): s_setprio(1) around each MFMA compute block — with 2 waves/SIMD at
// different phases (one in pinned load-issue, one at MFMA), priority lets the
// MFMA-ready wave win issue slots (T5; requires phase diversity, which the
// pinned load/compute split provides).
template<int K, int KTL>
__device__ __forceinline__ void gemm2(const i32x4& srdA, int voA,
    const u16* __restrict__ bA, const u16* __restrict__ bB,
    const u16* __restrict__ bP, int lane, f32x4 (&acc)[4]) {
  constexpr int NK = K / 32;
  const int lo = lane * 8;

  if constexpr (KTL == 0) {
    // degraded-mode fallback (nx<32 only): simple r4-style loop
    const u16* p0 = bA;
    const u16* p1 = bA + (size_t)NK * 512;
    const u16* q2 = bB;
    const u16* q3 = bB + (size_t)NK * 512;
#pragma unroll 8
    for (int kt = 0; kt < NK; ++kt) {
      i32x4 a0 = llvm_amdgcn_raw_buffer_load_i32x4(srdA, voA + kt * 64, 0, AUX_SC0);
      mf1(a0, p0, p1, q2, q3, (size_t)kt * 512, lo, acc);
    }
  } else {
    constexpr int NGP = KTL / 8;          // prefix groups of 8 (KTL0=32->4, KTL1=16->2)
    constexpr int NGS = (NK - KTL) / 4;   // suffix groups of 4 (L0: 4, L1: 12)
    const u16* p0 = bA;
    const u16* p1 = bA + (size_t)NK * 512;
    const u16* bP3 = bP + (size_t)KTL * 512;
    i32x4 srdB = make_srd(bB);
    const int lob = lane * 16;            // byte offset of this lane's 16B in a kt-slice

    i32x4 aE[8], aO[8];
    i32x4 sAE[4], sBE[8], sAO[4], sBO[8];

#pragma unroll
    for (int j = 0; j < 8; ++j)
      aE[j] = llvm_amdgcn_raw_buffer_load_i32x4(srdA, voA + j * 64, 0, AUX_SC0);

#pragma unroll
    for (int g = 0; g < NGP; ++g) {
      if (g + 1 < NGP) {
#pragma unroll
        for (int j = 0; j < 8; ++j) {
          i32x4 v = llvm_amdgcn_raw_buffer_load_i32x4(srdA, voA + ((g + 1) * 8 + j) * 64, 0, AUX_SC0);
          if ((g & 1) == 0) aO[j] = v; else aE[j] = v;
        }
      } else {
        // last prefix group: prefetch suffix group 0 (4 A + 8 B)
#pragma unroll
        for (int j = 0; j < 4; ++j) {
          sAE[j] = llvm_amdgcn_raw_buffer_load_i32x4(srdA, voA + (KTL + j) * 64, 0, AUX_SC0);
          sBE[2 * j]     = llvm_amdgcn_raw_buffer_load_i32x4(srdB, (0 * NK + KTL + j) * 1024 + lob, 0, AUX_L1);
          sBE[2 * j + 1] = llvm_amdgcn_raw_buffer_load_i32x4(srdB, (1 * NK + KTL + j) * 1024 + lob, 0, AUX_L1);
        }
      }
      __builtin_amdgcn_sched_barrier(0);   // pin: loads above, compute below
      __builtin_amdgcn_s_setprio(1);
#pragma unroll
      for (int j = 0; j < 8; ++j) {
        const int kt = g * 8 + j;
        if ((g & 1) == 0) mf1(aE[j], p0, p1, bP, bP3, (size_t)kt * 512, lo, acc);
        else              mf1(aO[j], p0, p1, bP, bP3, (size_t)kt * 512, lo, acc);
      }
      __builtin_amdgcn_s_setprio(0);
      __builtin_amdgcn_sched_barrier(0);   // pin: this group's compute before next issue
    }

#pragma unroll
    for (int s = 0; s < NGS; ++s) {
      if (s + 1 < NGS) {
        const int kb = KTL + (s + 1) * 4;
#pragma unroll
        for (int j = 0; j < 4; ++j) {
          i32x4 va = llvm_amdgcn_raw_buffer_load_i32x4(srdA, voA + (kb + j) * 64, 0, AUX_SC0);
          i32x4 v2 = llvm_amdgcn_raw_buffer_load_i32x4(srdB, (0 * NK + kb + j) * 1024 + lob, 0, AUX_L1);
          i32x4 v3 = llvm_amdgcn_raw_buffer_load_i32x4(srdB, (1 * NK + kb + j) * 1024 + lob, 0, AUX_L1);
          if ((s & 1) == 0) { sAO[j] = va; sBO[2 * j] = v2; sBO[2 * j + 1] = v3; }
          else              { sAE[j] = va; sBE[2 * j] = v2; sBE[2 * j + 1] = v3; }
        }
      }
      __builtin_amdgcn_sched_barrier(0);   // pin: loads above, compute below
      __builtin_amdgcn_s_setprio(1);
#pragma unroll
      for (int j = 0; j < 4; ++j) {
        const int kt = KTL + s * 4 + j;
        if ((s & 1) == 0) mf1r(sAE[j], p0, p1, (size_t)kt * 512, lo, sBE[2 * j], sBE[2 * j + 1], acc);
        else              mf1r(sAO[j], p0, p1, (size_t)kt * 512, lo, sBO[2 * j], sBO[2 * j + 1], acc);
      }
      __builtin_amdgcn_s_setprio(0);
      __builtin_amdgcn_sched_barrier(0);   // pin: compute before next group's issue
    }
  }
}

// layer-0 job jl (0..15): stage emb(tk+1) for rows jl*8..+8, then h0'(tk) GEMM
__device__ __forceinline__ void do_l0(int tk, int xcc, int jl, bool uselds,
    const u16* __restrict__ ldsb, const u16* __restrict__ Wt0,
    const int* __restrict__ inputs, const float* __restrict__ emb,
    const float* __restrict__ b0, u16* __restrict__ A0, u16* __restrict__ A1,
    int tid)
{
  const int lane = tid & 63, w = tid >> 6, q = lane >> 4, l16 = lane & 15;
  const int c0 = jl * 64;
  if (tk < TT - 1) {
    // 512 threads: 8 rows x 64 threads, 8 f32 -> 8 bf16 each
    const int grow = xcc * 128 + jl * 8 + (tid >> 6);
    const int c = (tid & 63) * 8;
    const int idx = inputs[grow * TT + tk + 1];
    const f32x4* s = (const f32x4*)(emb + (size_t)idx * EE + c);
    f32x4 f0 = s[0], f1 = s[1];
    u16x8 oa;
#pragma unroll
    for (int j = 0; j < 4; ++j) { oa[j] = f2bf(f0[j]); oa[j + 4] = f2bf(f1[j]); }
    *(u16x8*)(A0 + (size_t)((tk + 1) & 1) * HN0 + (size_t)grow * K0 + c) = oa;
  }
  if (tk < TT) {
    f32x4 acc[4];
#pragma unroll
    for (int n = 0; n < 4; ++n) acc[n] = (f32x4){0.f, 0.f, 0.f, 0.f};
    i32x4 srdA = make_srd(A0 + (size_t)(tk & 1) * HN0);
    const int voA = ((xcc * 128 + w * 16 + l16) * K0 + q * 8) * 2;
    const u16* gA = Wt0 + (size_t)(c0 / 16) * NK0 * 512;
    const u16* bB = Wt0 + (size_t)(c0 / 16 + 2) * NK0 * 512;
    if (uselds) gemm2<K0, KTL0>(srdA, voA, ldsb, bB,
                                ldsb + (size_t)2 * NK0 * 512, lane, acc);
    else        gemm2<K0, 0   >(srdA, voA, gA, bB, ldsb, lane, acc);
    u16* d1 = A1 + (size_t)(tk & 1) * HN1;              // h0' -> layer-1 input (same XCD)
    u16* d2 = A0 + (size_t)((tk + 1) & 1) * HN0 + 512;  // h0 recurrent
#pragma unroll
    for (int n = 0; n < 4; ++n) {
      const int col = c0 + n * 16 + l16;
      const float bs = b0[col];
#pragma unroll
      for (int rr = 0; rr < 4; ++rr) {
        const int grow = xcc * 128 + w * 16 + q * 4 + rr;
        const u16 v = f2bf(fast_tanh(acc[n][rr] + bs));
        d1[(size_t)grow * K1 + col] = v;
        d2[(size_t)grow * K0 + col] = v;
      }
    }
  }
}

// layer-1 job jl (0..15): h1(tk-1) GEMM
__device__ __forceinline__ void do_l1(int tk, int xcc, int jl, bool uselds,
    const u16* __restrict__ ldsb, const u16* __restrict__ Wt1,
    const float* __restrict__ b1, u16* __restrict__ A1, int tid)
{
  const int lane = tid & 63, w = tid >> 6, q = lane >> 4, l16 = lane & 15;
  const int c0 = jl * 64;
  f32x4 acc[4];
#pragma unroll
  for (int n = 0; n < 4; ++n) acc[n] = (f32x4){0.f, 0.f, 0.f, 0.f};
  i32x4 srdA = make_srd(A1 + (size_t)((tk - 1) & 1) * HN1);
  const int voA = ((xcc * 128 + w * 16 + l16) * K1 + q * 8) * 2;
  const u16* gA = Wt1 + (size_t)(c0 / 16) * NK1 * 512;
  const u16* bB = Wt1 + (size_t)(c0 / 16 + 2) * NK1 * 512;
  if (uselds) gemm2<K1, KTL1>(srdA, voA, ldsb, bB,
                              ldsb + (size_t)2 * NK1 * 512, lane, acc);
  else        gemm2<K1, 0   >(srdA, voA, gA, bB, ldsb, lane, acc);
  u16* d1 = A1 + (size_t)(tk & 1) * HN1 + 1024;         // h1 recurrent
#pragma unroll
  for (int n = 0; n < 4; ++n) {
    const int col = c0 + n * 16 + l16;
    const float bs = b1[col];
#pragma unroll
    for (int rr = 0; rr < 4; ++rr) {
      const int grow = xcc * 128 + w * 16 + q * 4 + rr;
      d1[(size_t)grow * K1 + col] = f2bf(fast_tanh(acc[n][rr] + bs));
    }
  }
}

__global__ __launch_bounds__(NTHR, 2)
void rnn_kernel(const int* __restrict__ inputs, const float* __restrict__ emb,
    const float* __restrict__ W0, const float* __restrict__ U0, const float* __restrict__ b0,
    const float* __restrict__ W1, const float* __restrict__ U1, const float* __restrict__ b1,
    const float* __restrict__ Wout, const float* __restrict__ bout,
    float* __restrict__ out,
    u16* __restrict__ Wt0, u16* __restrict__ Wt1,
    u16* __restrict__ A0, u16* __restrict__ A1, int* __restrict__ bar)
{
  extern __shared__ u16 lds[];
  int* li = (int*)lds;
  cg::grid_group grid = cg::this_grid();
  const int tid = threadIdx.x, bid = blockIdx.x;

  // ---- startup (grid-distributed): weights, emb(0), zero states + barrier area ----
  const int gstart = bid * NTHR + tid;
  wfill<K0, 512>(Wt0, W0, U0, gstart);
  wfill<K1, 1024>(Wt1, W1, U1, gstart);
  for (int g = gstart; g < BB * EE / 8; g += NBLK * NTHR) {
    const int b = g >> 6, seg = g & 63;
    const int idx = inputs[b * TT];
    const f32x4* s = (const f32x4*)(emb + (size_t)idx * EE + seg * 8);
    f32x4 f0 = s[0], f1 = s[1];
    u16x8 o;
#pragma unroll
    for (int j = 0; j < 4; ++j) { o[j] = f2bf(f0[j]); o[j + 4] = f2bf(f1[j]); }
    *(u16x8*)(A0 + (size_t)b * K0 + seg * 8) = o;
  }
  {
    const u16x8 z = {0, 0, 0, 0, 0, 0, 0, 0};
    for (int g = gstart; g < BB * 1024 / 8; g += NBLK * NTHR) {
      const int b = g >> 7, seg = g & 127;
      *(u16x8*)(A0 + (size_t)b * K0 + 512 + seg * 8) = z;      // h0(-1) = 0
      *(u16x8*)(A1 + (size_t)b * K1 + 1024 + seg * 8) = z;     // h1(-1) = 0
    }
  }
  if (bid == 0) for (int i = tid; i < BAR_INTS; i += NTHR) bar[i] = 0;
  grid.sync();

  // ---- roster: true XCD + slot; second sync publishes per-XCD counts ----
  if (tid == 0) {
    const int xc = __builtin_amdgcn_s_getreg((7 << 11) | 20) & 7;   // HW_REG_XCC_ID
    li[0] = xc;
    li[1] = atomicAdd(&bar[ROSTER_BASE + xc], 1);
  }
  __syncthreads();
  const int xcc = li[0], slot = li[1];
  __syncthreads();
  grid.sync();
  if (tid == 0)
    li[0] = __hip_atomic_load(&bar[ROSTER_BASE + xcc],
                              __ATOMIC_RELAXED, __HIP_MEMORY_SCOPE_AGENT);
  __syncthreads();
  const int nx = li[0];
  __syncthreads();

  // ---- primary job's weights -> LDS: bA (2 frag-cols) + bB kt-prefix (tick-invariant) ----
  if (slot < 32) {
    const bool pL0 = slot < 16;
    const int cb = (pL0 ? slot : slot - 16) * 4;
    const int NKp = pL0 ? NK0 : NK1;
    const int KTLp = pL0 ? KTL0 : KTL1;
    const u16* W = pL0 ? Wt0 : Wt1;
    const u16x8* s = (const u16x8*)(W + (size_t)cb * NKp * 512);
    const int nv = 2 * NKp * 64;
    u16x8* d = (u16x8*)lds;
    for (int i = tid; i < nv; i += NTHR) d[i] = s[i];
    // bB prefix: frag-cols cb+2, cb+3 for kt < KTLp; dest layout (f*KTLp + kt)*512 + lane*8
    u16x8* d2 = d + nv;
    const int nv2 = 2 * KTLp * 64;
    for (int i = tid; i < nv2; i += NTHR) {
      const int f = i / (KTLp * 64);
      const int rem = i - f * (KTLp * 64);
      d2[i] = *((const u16x8*)(W + (size_t)(cb + 2 + f) * NKp * 512) + rem);
    }
  }
  __syncthreads();

  // ---- tick loop: jobs 0..15 = layer0 stripes, 16..31 = layer1 stripes (lagged) ----
  for (int tk = 0; tk <= TT; ++tk) {
    for (int job = slot; job < 32; job += nx) {
      const bool uselds = (job == slot);
      if (job < 16) do_l0(tk, xcc, job, uselds, lds, Wt0, inputs, emb, b0, A0, A1, tid);
      else if (tk >= 1) do_l1(tk, xcc, job - 16, uselds, lds, Wt1, b1, A1, tid);
    }
    xbar(bar, xcc, slot, nx, tk + 1, tid);
  }

  // ---- output (slot 0 per XCD): sigmoid(h1(255) @ Wout + bout) for 128 local rows ----
  if (slot == 0) {
    const int lane = tid & 63, w = tid >> 6;   // 8 waves x 16 rows
    i32x4 srdH = make_srd(A1);
    const f32x4* wv = (const f32x4*)(Wout + lane * 16);
    f32x4 w0 = wv[0], w1 = wv[1], w2 = wv[2], w3 = wv[3];
    for (int rr = 0; rr < 16; ++rr) {
      const int grow = xcc * 128 + w * 16 + rr;
      const int vo = (grow * K1 + 1024 + lane * 16) * 2;
      i32x4 hv0 = llvm_amdgcn_raw_buffer_load_i32x4(srdH, vo, 0, AUX_SC0);
      i32x4 hv1 = llvm_amdgcn_raw_buffer_load_i32x4(srdH, vo + 16, 0, AUX_SC0);
      u16x8 lo = __builtin_bit_cast(u16x8, hv0);
      u16x8 hi = __builtin_bit_cast(u16x8, hv1);
      float s = 0.f;
#pragma unroll
      for (int j = 0; j < 4; ++j) {
        s += bf2f(lo[j]) * w0[j];
        s += bf2f(lo[j + 4]) * w1[j];
        s += bf2f(hi[j]) * w2[j];
        s += bf2f(hi[j + 4]) * w3[j];
      }
#pragma unroll
      for (int off = 32; off > 0; off >>= 1) s += __shfl_down(s, off);
      if (lane == 0) out[grow] = 1.f / (1.f + expf(-(s + bout[0])));
    }
  }
}

extern "C" void kernel_launch(void* const* d_in, const int* in_sizes, int n_in,
                              void* d_out, int out_size, void* d_ws, size_t ws_size,
                              hipStream_t stream)
{
  (void)in_sizes; (void)n_in; (void)out_size; (void)ws_size;
  const int*   inputs = (const int*)d_in[0];
  const float* emb    = (const float*)d_in[1];
  const float* W0     = (const float*)d_in[2];
  const float* U0     = (const float*)d_in[3];
  const float* b0     = (const float*)d_in[4];
  const float* W1     = (const float*)d_in[5];
  const float* U1     = (const float*)d_in[6];
  const float* b1     = (const float*)d_in[7];
  const float* Wout   = (const float*)d_in[8];
  const float* bout   = (const float*)d_in[9];
  float* out = (float*)d_out;

  // ws (u16): Wt0 [1024*K0], Wt1 [1024*K1], A0 [2][1024*K0], A1 [2][1024*K1], bar
  u16* Wt0 = (u16*)d_ws;
  u16* Wt1 = Wt0 + (size_t)1024 * K0;
  u16* A0  = Wt1 + (size_t)1024 * K1;
  u16* A1  = A0 + (size_t)2 * 1024 * K0;
  int* bar = (int*)(A1 + (size_t)2 * 1024 * K1);

  static int lds_set = 0;
  if (!lds_set) {
    hipFuncSetAttribute((const void*)rnn_kernel,
                        hipFuncAttributeMaxDynamicSharedMemorySize, LDS_BYTES);
    lds_set = 1;
  }

  void* args[] = { &inputs, &emb, &W0, &U0, &b0, &W1, &U1, &b1, &Wout, &bout,
                   &out, &Wt0, &Wt1, &A0, &A1, &bar };
  hipLaunchCooperativeKernel((void*)rnn_kernel, dim3(NBLK), dim3(NTHR), args, LDS_BYTES, stream);
}